// Round 9
// baseline (106.772 us; speedup 1.0000x reference)
//
#include <hip/hip_runtime.h>
#include <hip/hip_bf16.h>

// Problem constants (fixed by reference setup_inputs)
constexpr int NWIN = 49;     // 7x7 windows
constexpr int QLD  = 52;     // padded row length for 49-length rows (13 float4)

// workspace layout (float offsets)
constexpr int OFF_Q    = 26624;        // [2][128][4][52]  = 53248 (b, d, t, n)
constexpr int OFF_QSP  = 79872;        // [2][4][8192]     swizzled (b, t, w)
constexpr int OFF_A12T = 169984;       // [2][3][64][64] (t=1,2 written)
constexpr int OFF_A21  = 194560;       // (t=2 written)
constexpr int OFF_A21T = 219136;       // (t=0 written)
constexpr int OFF_R1T  = 251904;       // [2][4096]  R1^T = A21_0^T @ A21_1^T
constexpr int OFF_L    = 260096;       // [2][4096]  L    = P @ A12_2
constexpr int OFF_BAR  = 276480;       // 4 ints (barrier counters)
constexpr int OFF_H    = 276608;       // [8][64][64] cell histograms = 32768

// ---------------------------------------------------------------------------
// K1: fused front end — blocks [0,98): q head (first: longest pole overlaps
// the cheap cell blocks); blocks [98,610): per-cell histograms (proven R8).
__global__ void __launch_bounds__(256, 1)
k_front(const int* __restrict__ mask, const float* __restrict__ feats,
        const float* __restrict__ Wh, float* __restrict__ h, float* __restrict__ q) {
    if (blockIdx.x < 98) {
        int bid = blockIdx.x;
        int n = bid % NWIN, b = bid / NWIN;
        __shared__ float4 f4[512];          // feats[c][t] as float4 over t
        __shared__ float4 psum4[8 * 129];   // [ch][129] (pad kills bank conflict)
        __shared__ float4 red4[2];
        const float4* fp4 = (const float4*)(feats + (size_t)(b * NWIN + n) * 2048);
        for (int i = threadIdx.x; i < 512; i += 256) f4[i] = fp4[i];
        __syncthreads();

        int dl = threadIdx.x & 31, ch = threadIdx.x >> 5;   // ch in 0..7
        const float4* wh4 = (const float4*)Wh;              // [c][32] f4 over d
        float a0x=0.f,a0y=0.f,a0z=0.f,a0w=0.f;
        float a1x=0.f,a1y=0.f,a1z=0.f,a1w=0.f;
        float a2x=0.f,a2y=0.f,a2z=0.f,a2w=0.f;
        float a3x=0.f,a3y=0.f,a3z=0.f,a3w=0.f;
        int c0 = ch * 64;
        #pragma unroll 8
        for (int cc = 0; cc < 64; ++cc) {
            int c = c0 + cc;
            float4 w4 = wh4[c * 32 + dl];
            float4 fv = f4[c];
            a0x += fv.x * w4.x; a0y += fv.y * w4.x; a0z += fv.z * w4.x; a0w += fv.w * w4.x;
            a1x += fv.x * w4.y; a1y += fv.y * w4.y; a1z += fv.z * w4.y; a1w += fv.w * w4.y;
            a2x += fv.x * w4.z; a2y += fv.y * w4.z; a2z += fv.z * w4.z; a2w += fv.w * w4.z;
            a3x += fv.x * w4.w; a3y += fv.y * w4.w; a3z += fv.z * w4.w; a3w += fv.w * w4.w;
        }
        psum4[ch * 129 + dl * 4 + 0] = make_float4(a0x, a0y, a0z, a0w);
        psum4[ch * 129 + dl * 4 + 1] = make_float4(a1x, a1y, a1z, a1w);
        psum4[ch * 129 + dl * 4 + 2] = make_float4(a2x, a2y, a2z, a2w);
        psum4[ch * 129 + dl * 4 + 3] = make_float4(a3x, a3y, a3z, a3w);
        __syncthreads();

        float4 A;
        if (threadIdx.x < 128) {
            int d = threadIdx.x;
            A = psum4[d];
            #pragma unroll
            for (int c = 1; c < 8; ++c) {
                float4 p = psum4[c * 129 + d];
                A.x += p.x; A.y += p.y; A.z += p.z; A.w += p.w;
            }
            float sx = A.x * A.x, sy = A.y * A.y, sz = A.z * A.z, sw = A.w * A.w;
            for (int off = 32; off; off >>= 1) {
                sx += __shfl_down(sx, off); sy += __shfl_down(sy, off);
                sz += __shfl_down(sz, off); sw += __shfl_down(sw, off);
            }
            if ((threadIdx.x & 63) == 0) red4[threadIdx.x >> 6] = make_float4(sx, sy, sz, sw);
        }
        __syncthreads();
        if (threadIdx.x < 128) {
            float4 r0 = red4[0], r1 = red4[1];
            float ix = 1.f / fmaxf(sqrtf(r0.x + r1.x), 1e-12f);
            float iy = 1.f / fmaxf(sqrtf(r0.y + r1.y), 1e-12f);
            float iz = 1.f / fmaxf(sqrtf(r0.z + r1.z), 1e-12f);
            float iw = 1.f / fmaxf(sqrtf(r0.w + r1.w), 1e-12f);
            float* qb = q + (size_t)(b * 128 + (int)threadIdx.x) * 4 * QLD + n;
            qb[0 * QLD] = A.x * ix;
            qb[1 * QLD] = A.y * iy;
            qb[2 * QLD] = A.z * iz;
            qb[3 * QLD] = A.w * iw;
        }
    } else {
        int blkc = blockIdx.x - 98;
        int bt = blkc >> 6, cell = blkc & 63;
        int cy = cell >> 3, cx = cell & 7;
        __shared__ float loc[64];
        if (threadIdx.x < 64) loc[threadIdx.x] = 0.f;
        __syncthreads();
        const int* base = mask + bt * 65536 + (cy * 32) * 256 + cx * 32;
        #pragma unroll
        for (int it = 0; it < 4; ++it) {
            int idx = it * 256 + (int)threadIdx.x;
            int r = idx >> 5, c = idx & 31;
            int s = base[r * 256 + c];
            atomicAdd(&loc[s], 1.f);
        }
        __syncthreads();
        if (threadIdx.x < 64)
            h[(size_t)(bt * 64 + cell) * 64 + threadIdx.x] = loc[threadIdx.x];
    }
}

// ---------------------------------------------------------------------------
// K2: qsp in phase-A swizzled layout; ws rows assembled from cell histograms
// (proven R8). Also zeroes barrier counters + loss accumulator.
__global__ void k_qsp(const float* __restrict__ q, const float* __restrict__ hg,
                      float* __restrict__ qsp, float* __restrict__ out,
                      int* __restrict__ bar) {
    if (blockIdx.x == 0 && threadIdx.x < 4) {
        bar[threadIdx.x] = 0;
        if (threadIdx.x == 0) out[0] = 0.f;
    }
    int gid0 = blockIdx.x * 256;                 // [b:1][t:2][s:6][d:7]
    int t = (gid0 >> 13) & 3;
    int b = gid0 >> 15;
    int bt = b * 4 + t;
    int sbase = (gid0 >> 7) & 63;                // block covers s = sbase, sbase+1

    __shared__ float wrow[2][52];
    {
        int grp = threadIdx.x >> 7;              // 0 or 1
        int w = threadIdx.x & 127;
        if (w < 52) {
            float v = 0.f;
            if (w < 49) {
                int wy = w / 7, wx = w % 7;
                int s = sbase + grp;
                const float* hb = hg + (size_t)bt * 4096 + s;
                float wr0 = (wy >= 1 && wy <= 6) ? 0.5f : 1.f;
                float wr1 = (wy <= 5) ? 0.5f : 1.f;
                float wc0 = (wx >= 1 && wx <= 6) ? 0.5f : 1.f;
                float wc1 = (wx <= 5) ? 0.5f : 1.f;
                v = wr0 * wc0 * hb[(wy * 8 + wx) * 64]
                  + wr0 * wc1 * hb[(wy * 8 + wx + 1) * 64]
                  + wr1 * wc0 * hb[((wy + 1) * 8 + wx) * 64]
                  + wr1 * wc1 * hb[((wy + 1) * 8 + wx + 1) * 64];
            }
            wrow[grp][w] = v;                    // cols 49..51 zeroed
        }
    }
    __syncthreads();

    int tid = gid0 + threadIdx.x;
    int d = tid & 127;
    int s = (tid >> 7) & 63;
    const float4* qrow = (const float4*)(q + (size_t)((b * 128 + d) * 4 + t) * QLD);
    const float4* wr4 = (const float4*)wrow[threadIdx.x >> 7];
    float acc = 0.f, den = 0.f;
    #pragma unroll
    for (int i = 0; i < 13; ++i) {
        float4 w = wr4[i];
        float4 qv = qrow[i];
        den += w.x + w.y + w.z + w.w;
        acc += qv.x * w.x + qv.y * w.y + qv.z * w.z + qv.w * w.w;
    }
    int w = (s * 32 + ((d >> 2) ^ (s & 31))) * 4 + (d & 3);
    qsp[(size_t)bt * 8192 + w] = acc / (den + 1e-20f);
}

// ---------------------------------------------------------------------------
// Shared helpers. XOR-4-swizzled LDS matrix layout: element (r,k) lives at
// M[r*64 + (((k>>2)^(r&15))<<2)+(k&3)].

__device__ __forceinline__ void stage1(float* M, const float* __restrict__ G) {
    const float4* g = (const float4*)G;
    float4 v[4];
    #pragma unroll
    for (int it = 0; it < 4; ++it) v[it] = g[it * 256 + (int)threadIdx.x];
    #pragma unroll
    for (int it = 0; it < 4; ++it) {
        int idx = it * 256 + (int)threadIdx.x;
        int r = idx >> 4, c4 = (idx & 15) << 2;
        *(float4*)&M[r * 64 + (c4 ^ ((r & 15) << 2))] = v[it];
    }
}

// stage by waves 2-3 only (tid >= 128), 8 float4 per thread
__device__ __forceinline__ void stage1_h(float* M, const float* __restrict__ G) {
    int lt = (int)threadIdx.x - 128;   // 0..127
    const float4* g = (const float4*)G;
    #pragma unroll
    for (int it = 0; it < 8; ++it) {
        int idx = it * 128 + lt;
        int r = idx >> 4, c4 = (idx & 15) << 2;
        *(float4*)&M[r * 64 + (c4 ^ ((r & 15) << 2))] = g[idx];
    }
}

// 2-wave mm (tid<128), 8x4 tiles, K=64, swizzled operands.
// Per-output k-order identical to the proven 4-wave mm -> bit-identical.
// DS: 12 reads/kstep (vs 16 total before) -> 384 instrs/mm (was 512).
__device__ __forceinline__ void mm128_sw(float* acc, const float* Ra, const float* Rb) {
    int lt = threadIdx.x;              // < 128
    int nl = lt >> 4, ml = lt & 15;    // nl 0..7, ml 0..15
    int sxa0 = nl << 2, sxa1 = (nl + 8) << 2, sxb = ml << 2;
    #pragma unroll
    for (int i = 0; i < 32; ++i) acc[i] = 0.f;
    #pragma unroll 2
    for (int k0 = 0; k0 < 64; k0 += 4) {
        float4 av[8], bv[4];
        #pragma unroll
        for (int i = 0; i < 8; ++i)
            av[i] = *(const float4*)&Ra[(nl + 8 * i) * 64 + (k0 ^ ((i & 1) ? sxa1 : sxa0))];
        #pragma unroll
        for (int j = 0; j < 4; ++j)
            bv[j] = *(const float4*)&Rb[(ml + 16 * j) * 64 + (k0 ^ sxb)];
        #pragma unroll
        for (int i = 0; i < 8; ++i)
            #pragma unroll
            for (int j = 0; j < 4; ++j)
                acc[i * 4 + j] += av[i].x * bv[j].x + av[i].y * bv[j].y
                                + av[i].z * bv[j].z + av[i].w * bv[j].w;
    }
}

// write 8x4 acc rows into swizzled LDS (tid<128)
__device__ __forceinline__ void wr128_sw(float* M, const float* acc) {
    int nl = threadIdx.x >> 4, ml = threadIdx.x & 15;
    #pragma unroll
    for (int i = 0; i < 8; ++i)
        #pragma unroll
        for (int j = 0; j < 4; ++j) {
            int r = nl + 8 * i, k = ml + 16 * j;
            M[r * 64 + (((k & ~3) ^ ((r & 15) << 2)) | (k & 3))] = acc[i * 4 + j];
        }
}

// store 8x4 acc row-major to global (tid<128)
__device__ __forceinline__ void store_mat128(float* __restrict__ G, const float* acc) {
    int nl = threadIdx.x >> 4, ml = threadIdx.x & 15;
    #pragma unroll
    for (int i = 0; i < 8; ++i)
        #pragma unroll
        for (int j = 0; j < 4; ++j)
            G[(nl + 8 * i) * 64 + ml + 16 * j] = acc[i * 4 + j];
}

// aa store + fused loss for the 8x4 mapping. Called by ALL 256 threads
// (acc meaningful only for tid<128; barrier inside is unconditional).
// Diag of row n=nl+8i: col n -> holder j = i>>1 (8(i&1)+16(i>>1) = 8i),
// source lane (l&48)|(nl+8*(i&1)) — same 16-lane group.
__device__ __forceinline__ void store_loss128(const float* acc, float* __restrict__ aa,
                                              float* __restrict__ out, float* red) {
    int tid = threadIdx.x;
    if (tid < 128) {
        int nl = tid >> 4, ml = tid & 15;
        #pragma unroll
        for (int i = 0; i < 8; ++i)
            #pragma unroll
            for (int j = 0; j < 4; ++j)
                aa[(nl + 8 * i) * 64 + ml + 16 * j] = acc[i * 4 + j];
        int l = tid & 63;
        float part = 0.f;
        #pragma unroll
        for (int i = 0; i < 8; ++i) {
            float rsum = acc[i * 4 + 0] + acc[i * 4 + 1] + acc[i * 4 + 2] + acc[i * 4 + 3];
            rsum += __shfl_down(rsum, 8, 16);
            rsum += __shfl_down(rsum, 4, 16);
            rsum += __shfl_down(rsum, 2, 16);
            rsum += __shfl_down(rsum, 1, 16);
            float dv = __shfl(acc[i * 4 + (i >> 1)], (l & 48) | (nl + 8 * (i & 1)), 64);
            if ((l & 15) == 0) part += logf(rsum + 6.4e-19f) - logf(dv + 1e-20f);
        }
        for (int off = 32; off; off >>= 1) part += __shfl_down(part, off);
        if (l == 0) red[tid >> 6] = part;    // red[0], red[1]
    }
    __syncthreads();
    if (tid == 0) atomicAdd(out, (red[0] + red[1]) * (1.f / 128.f));
}

// Leader-fenced device barrier (proven R7). Participants <= 6 only
// (barrier cost ~linear in participants; 16 was +8.5us, 256 was +36us).
__device__ __forceinline__ void gbar(int* cnt, int target) {
    __syncthreads();
    if (threadIdx.x == 0) {
        __threadfence();
        __hip_atomic_fetch_add(cnt, 1, __ATOMIC_ACQ_REL, __HIP_MEMORY_SCOPE_AGENT);
        while (__hip_atomic_load(cnt, __ATOMIC_ACQUIRE, __HIP_MEMORY_SCOPE_AGENT) < target)
            __builtin_amdgcn_s_sleep(2);
        __threadfence();
    }
    __syncthreads();
}

// ---------------------------------------------------------------------------
// K3: fused As+zero_softmax+chain. grid = 6, block = 256, TWO device barriers.
// All mms are 2-wave 8x4 (waves 0-1); waves 2-3 stage the next operand
// concurrently. Staging of sibling-produced matrices stays AFTER gbar0
// (they are written in phase A by other blocks — prefetch would race).
__global__ void __launch_bounds__(256, 1)
k_tail(const float* __restrict__ qsp,
       float* __restrict__ a12T, float* __restrict__ a21, float* __restrict__ a21T,
       float* __restrict__ wsR1T, float* __restrict__ wsL,
       float* __restrict__ out, int* __restrict__ bar) {
    __shared__ float SM[16384];           // 64 KB, aliased per phase
    float* M0 = SM;
    float* M1 = SM + 4096;
    float* M2 = SM + 8192;
    float* M3 = SM + 12288;
    const int tid = threadIdx.x;
    const int blk = blockIdx.x;
    const int t = blk % 3, b = blk / 3;

    // ---------------- phase A: As + zero_softmax (2-wave mm) ---------------
    {
        float4* qaT4 = (float4*)SM;              // [64][32] swizzled (s-major)
        float4* qbT4 = (float4*)SM + 2048;
        {
            const float4* gA = (const float4*)(qsp + (size_t)(b * 4 + t) * 8192);
            const float4* gB = (const float4*)(qsp + (size_t)(b * 4 + t + 1) * 8192);
            #pragma unroll
            for (int it = 0; it < 8; ++it) {
                int idx = it * 256 + tid;
                qaT4[idx] = gA[idx];
                qbT4[idx] = gB[idx];
            }
        }
        __syncthreads();

        const int nl = tid >> 4, ml = tid & 15;  // 8x4 semantics for tid<128
        float acc[32];
        if (tid < 128) {
            #pragma unroll
            for (int i = 0; i < 32; ++i) acc[i] = 0.f;
            #pragma unroll 2
            for (int k4 = 0; k4 < 32; ++k4) {
                float4 av[8], bv[4];
                #pragma unroll
                for (int i = 0; i < 8; ++i) {
                    int n = nl + 8 * i;               // (n&31) = nl + 8*(i&3)
                    av[i] = qaT4[n * 32 + (k4 ^ (nl + 8 * (i & 3)))];
                }
                #pragma unroll
                for (int j = 0; j < 4; ++j) {
                    int m = ml + 16 * j;              // (m&31) = ml + 16*(j&1)
                    bv[j] = qbT4[m * 32 + (k4 ^ (ml + 16 * (j & 1)))];
                }
                #pragma unroll
                for (int i = 0; i < 8; ++i)
                    #pragma unroll
                    for (int j = 0; j < 4; ++j)
                        acc[i * 4 + j] += av[i].x * bv[j].x + av[i].y * bv[j].y
                                        + av[i].z * bv[j].z + av[i].w * bv[j].w;
            }
        }
        __syncthreads();

        float* eb = (float*)qaT4;          // [64][65] (floats 0..4159)
        float* rs = (float*)qbT4;          // [64]     (floats 8192..)
        float* cs = rs + 64;               // [64]
        if (tid < 128) {
            #pragma unroll
            for (int i = 0; i < 8; ++i)
                #pragma unroll
                for (int j = 0; j < 4; ++j) {
                    int n = nl + 8 * i, m = ml + 16 * j;
                    float x = acc[i * 4 + j] * (1.f / 0.07f);
                    float e = expf(x) - 1.f;
                    eb[n * 65 + m] = e * e;
                }
        }
        __syncthreads();
        if (tid < 128) {
            int r = tid & 63; bool isrow = tid < 64;
            float a = 0.f;
            #pragma unroll
            for (int k = 0; k < 64; ++k) a += isrow ? eb[r * 65 + k] : eb[k * 65 + r];
            (isrow ? rs : cs)[r] = a + 1e-5f;
        }
        __syncthreads();
        // Output section reads only LDS -> run on all 4 waves (4x4 mapping).
        // t==0: A12_0 -> LDS M3 (local), A21_0^T -> global.
        // t==1: A12_1^T -> global, A21_1 -> LDS M3 (local).
        // t==2: both -> global.
        {
            int nl4 = tid >> 4, ml4 = tid & 15;
            float* p12T = a12T + (b * 3 + t) * 4096;
            float* p21  = a21  + (b * 3 + t) * 4096;
            float* p21T = a21T + (b * 3 + t) * 4096;
            #pragma unroll
            for (int i = 0; i < 4; ++i)
                #pragma unroll
                for (int j = 0; j < 4; ++j) {
                    int n = nl4 + 16 * i, m = ml4 + 16 * j;
                    float v   = eb[n * 65 + m];
                    float v12 = v / rs[n];           // A12[n][m]
                    float v21 = v / cs[m];           // A21[m][n]
                    if (t == 0) {
                        M3[n * 64 + (((m & ~3) ^ ((n & 15) << 2)) | (m & 3))] = v12;
                        p21T[n * 64 + m] = v21;
                    } else if (t == 1) {
                        p12T[m * 64 + n] = v12;
                        M3[m * 64 + (((n & ~3) ^ ((m & 15) << 2)) | (n & 3))] = v21;
                    } else {
                        p12T[m * 64 + n] = v12;
                        p21 [m * 64 + n] = v21;
                    }
                }
        }
    }
    gbar(bar + 0, 6);
    if (t == 2) return;                   // blocks 2,5 done (arrived at bar0)
    const bool odd = (t == 1);

    // ---------------- phase B': 2 mms (waves 0-1) + overlapped staging -----
    if (!odd) {
        // P = A12_0(M3) @ A12_1 ; L = P @ A12_2 -> wsL
        stage1(M0, a12T + (b * 3 + 1) * 4096);    // A12_1^T rows (all threads)
        __syncthreads();
        float accP[32];
        if (tid < 128) mm128_sw(accP, M3, M0);    // P
        else stage1_h(M2, a12T + (b * 3 + 2) * 4096);  // A12_2^T rows (overlap)
        if (tid < 128) wr128_sw(M1, accP);        // P rows, local
        __syncthreads();
        float accL[32];
        if (tid < 128) {
            mm128_sw(accL, M1, M2);               // L = P @ A12_2
            store_mat128(wsL + b * 4096, accL);   // partner needs L
        }
    } else {
        // R1T = A21_0^T @ A21_1(M3) ; RT = R1T @ A21_2^T (kept local in M0)
        stage1(M0, a21T + (b * 3 + 0) * 4096);    // A21_0^T rows
        __syncthreads();
        float accR[32];
        if (tid < 128) mm128_sw(accR, M0, M3);    // R1T
        else stage1_h(M2, a21 + (b * 3 + 2) * 4096);   // A21_2 rows (overlap)
        if (tid < 128) {
            store_mat128(wsR1T + b * 4096, accR); // partner needs R1T
            wr128_sw(M1, accR);                   // R1T rows, local
        }
        __syncthreads();
        float accRT[32];
        if (tid < 128) {
            mm128_sw(accRT, M1, M2);              // RT[n][m] = (A21_2@R1)^T
            wr128_sw(M0, accRT);                  // RT rows, local (Rb of aa2)
        }
    }
    gbar(bar + 1, 4);

    // ---------------- phase C': final mms + fused loss ---------------------
    if (!odd) {
        // aa1_b = P @ R1 : Ra = M1 (P, resident), Rb = R1T_b staged
        stage1(M2, wsR1T + b * 4096);
        __syncthreads();
        float acc[32];
        if (tid < 128) mm128_sw(acc, M1, M2);
        store_loss128(acc, out + 1 + b * 4096, out, M0);
    } else {
        // aa2_b = L @ R : Ra = L_b staged, Rb = M0 (RT, resident)
        stage1(M2, wsL + b * 4096);
        __syncthreads();
        float acc[32];
        if (tid < 128) mm128_sw(acc, M2, M0);
        store_loss128(acc, out + 1 + (2 + b) * 4096, out, M1);
    }
}

// ---------------------------------------------------------------------------
extern "C" void kernel_launch(void* const* d_in, const int* in_sizes, int n_in,
                              void* d_out, int out_size, void* d_ws, size_t ws_size,
                              hipStream_t stream) {
    const float* feats = (const float*)d_in[0];
    const float* Wh    = (const float*)d_in[1];
    const int*   mask  = (const int*)d_in[2];
    float* out = (float*)d_out;
    float* ws  = (float*)d_ws;

    float* q       = ws + OFF_Q;
    float* qsp     = ws + OFF_QSP;
    float* a12T    = ws + OFF_A12T;
    float* a21     = ws + OFF_A21;
    float* a21T    = ws + OFF_A21T;
    float* wsR1T   = ws + OFF_R1T;
    float* wsL     = ws + OFF_L;
    float* h       = ws + OFF_H;
    int*   bar     = (int*)(ws + OFF_BAR);

    k_front<<<98 + 512, 256, 0, stream>>>(mask, feats, Wh, h, q);
    k_qsp<<<256, 256, 0, stream>>>(q, h, qsp, out, bar);
    k_tail<<<6, 256, 0, stream>>>(qsp, a12T, a21, a21T,
                                  wsR1T, wsL, out, bar);
}

// Round 10
// 99.947 us; speedup vs baseline: 1.0683x; 1.0683x over previous
//
#include <hip/hip_runtime.h>
#include <hip/hip_bf16.h>

// Problem constants (fixed by reference setup_inputs)
constexpr int NWIN = 49;     // 7x7 windows
constexpr int QLD  = 52;     // padded row length for 49-length rows (13 float4)

// workspace layout (float offsets)
constexpr int OFF_Q    = 26624;        // [2][128][4][52]  = 53248 (b, d, t, n)
constexpr int OFF_QSP  = 79872;        // [2][4][8192]     swizzled (b, t, w)
constexpr int OFF_A12T = 169984;       // [2][3][64][64] (t=1,2 written)
constexpr int OFF_A21  = 194560;       // (t=2 written)
constexpr int OFF_A21T = 219136;       // (t=0 written)
constexpr int OFF_R1T  = 251904;       // [2][4096]  R1^T = A21_0^T @ A21_1^T
constexpr int OFF_L    = 260096;       // [2][4096]  L    = P @ A12_2
constexpr int OFF_BAR  = 276480;       // 4 ints (barrier counters)
constexpr int OFF_H    = 276608;       // [8][64][64] cell histograms = 32768

// ---------------------------------------------------------------------------
// K1: fused front end — blocks [0,98): q head (first: longest pole overlaps
// the cheap cell blocks); blocks [98,610): per-cell histograms (proven R8).
__global__ void __launch_bounds__(256, 1)
k_front(const int* __restrict__ mask, const float* __restrict__ feats,
        const float* __restrict__ Wh, float* __restrict__ h, float* __restrict__ q) {
    if (blockIdx.x < 98) {
        int bid = blockIdx.x;
        int n = bid % NWIN, b = bid / NWIN;
        __shared__ float4 f4[512];          // feats[c][t] as float4 over t
        __shared__ float4 psum4[8 * 129];   // [ch][129] (pad kills bank conflict)
        __shared__ float4 red4[2];
        const float4* fp4 = (const float4*)(feats + (size_t)(b * NWIN + n) * 2048);
        for (int i = threadIdx.x; i < 512; i += 256) f4[i] = fp4[i];
        __syncthreads();

        int dl = threadIdx.x & 31, ch = threadIdx.x >> 5;   // ch in 0..7
        const float4* wh4 = (const float4*)Wh;              // [c][32] f4 over d
        float a0x=0.f,a0y=0.f,a0z=0.f,a0w=0.f;
        float a1x=0.f,a1y=0.f,a1z=0.f,a1w=0.f;
        float a2x=0.f,a2y=0.f,a2z=0.f,a2w=0.f;
        float a3x=0.f,a3y=0.f,a3z=0.f,a3w=0.f;
        int c0 = ch * 64;
        #pragma unroll 8
        for (int cc = 0; cc < 64; ++cc) {
            int c = c0 + cc;
            float4 w4 = wh4[c * 32 + dl];
            float4 fv = f4[c];
            a0x += fv.x * w4.x; a0y += fv.y * w4.x; a0z += fv.z * w4.x; a0w += fv.w * w4.x;
            a1x += fv.x * w4.y; a1y += fv.y * w4.y; a1z += fv.z * w4.y; a1w += fv.w * w4.y;
            a2x += fv.x * w4.z; a2y += fv.y * w4.z; a2z += fv.z * w4.z; a2w += fv.w * w4.z;
            a3x += fv.x * w4.w; a3y += fv.y * w4.w; a3z += fv.z * w4.w; a3w += fv.w * w4.w;
        }
        psum4[ch * 129 + dl * 4 + 0] = make_float4(a0x, a0y, a0z, a0w);
        psum4[ch * 129 + dl * 4 + 1] = make_float4(a1x, a1y, a1z, a1w);
        psum4[ch * 129 + dl * 4 + 2] = make_float4(a2x, a2y, a2z, a2w);
        psum4[ch * 129 + dl * 4 + 3] = make_float4(a3x, a3y, a3z, a3w);
        __syncthreads();

        float4 A;
        if (threadIdx.x < 128) {
            int d = threadIdx.x;
            A = psum4[d];
            #pragma unroll
            for (int c = 1; c < 8; ++c) {
                float4 p = psum4[c * 129 + d];
                A.x += p.x; A.y += p.y; A.z += p.z; A.w += p.w;
            }
            float sx = A.x * A.x, sy = A.y * A.y, sz = A.z * A.z, sw = A.w * A.w;
            for (int off = 32; off; off >>= 1) {
                sx += __shfl_down(sx, off); sy += __shfl_down(sy, off);
                sz += __shfl_down(sz, off); sw += __shfl_down(sw, off);
            }
            if ((threadIdx.x & 63) == 0) red4[threadIdx.x >> 6] = make_float4(sx, sy, sz, sw);
        }
        __syncthreads();
        if (threadIdx.x < 128) {
            float4 r0 = red4[0], r1 = red4[1];
            float ix = 1.f / fmaxf(sqrtf(r0.x + r1.x), 1e-12f);
            float iy = 1.f / fmaxf(sqrtf(r0.y + r1.y), 1e-12f);
            float iz = 1.f / fmaxf(sqrtf(r0.z + r1.z), 1e-12f);
            float iw = 1.f / fmaxf(sqrtf(r0.w + r1.w), 1e-12f);
            float* qb = q + (size_t)(b * 128 + (int)threadIdx.x) * 4 * QLD + n;
            qb[0 * QLD] = A.x * ix;
            qb[1 * QLD] = A.y * iy;
            qb[2 * QLD] = A.z * iz;
            qb[3 * QLD] = A.w * iw;
        }
    } else {
        int blkc = blockIdx.x - 98;
        int bt = blkc >> 6, cell = blkc & 63;
        int cy = cell >> 3, cx = cell & 7;
        __shared__ float loc[64];
        if (threadIdx.x < 64) loc[threadIdx.x] = 0.f;
        __syncthreads();
        const int* base = mask + bt * 65536 + (cy * 32) * 256 + cx * 32;
        #pragma unroll
        for (int it = 0; it < 4; ++it) {
            int idx = it * 256 + (int)threadIdx.x;
            int r = idx >> 5, c = idx & 31;
            int s = base[r * 256 + c];
            atomicAdd(&loc[s], 1.f);
        }
        __syncthreads();
        if (threadIdx.x < 64)
            h[(size_t)(bt * 64 + cell) * 64 + threadIdx.x] = loc[threadIdx.x];
    }
}

// ---------------------------------------------------------------------------
// K2: qsp in phase-A swizzled layout; ws rows assembled from cell histograms
// (proven R8). Also zeroes barrier counters + loss accumulator.
__global__ void k_qsp(const float* __restrict__ q, const float* __restrict__ hg,
                      float* __restrict__ qsp, float* __restrict__ out,
                      int* __restrict__ bar) {
    if (blockIdx.x == 0 && threadIdx.x < 4) {
        bar[threadIdx.x] = 0;
        if (threadIdx.x == 0) out[0] = 0.f;
    }
    int gid0 = blockIdx.x * 256;                 // [b:1][t:2][s:6][d:7]
    int t = (gid0 >> 13) & 3;
    int b = gid0 >> 15;
    int bt = b * 4 + t;
    int sbase = (gid0 >> 7) & 63;                // block covers s = sbase, sbase+1

    __shared__ float wrow[2][52];
    {
        int grp = threadIdx.x >> 7;              // 0 or 1
        int w = threadIdx.x & 127;
        if (w < 52) {
            float v = 0.f;
            if (w < 49) {
                int wy = w / 7, wx = w % 7;
                int s = sbase + grp;
                const float* hb = hg + (size_t)bt * 4096 + s;
                float wr0 = (wy >= 1 && wy <= 6) ? 0.5f : 1.f;
                float wr1 = (wy <= 5) ? 0.5f : 1.f;
                float wc0 = (wx >= 1 && wx <= 6) ? 0.5f : 1.f;
                float wc1 = (wx <= 5) ? 0.5f : 1.f;
                v = wr0 * wc0 * hb[(wy * 8 + wx) * 64]
                  + wr0 * wc1 * hb[(wy * 8 + wx + 1) * 64]
                  + wr1 * wc0 * hb[((wy + 1) * 8 + wx) * 64]
                  + wr1 * wc1 * hb[((wy + 1) * 8 + wx + 1) * 64];
            }
            wrow[grp][w] = v;                    // cols 49..51 zeroed
        }
    }
    __syncthreads();

    int tid = gid0 + threadIdx.x;
    int d = tid & 127;
    int s = (tid >> 7) & 63;
    const float4* qrow = (const float4*)(q + (size_t)((b * 128 + d) * 4 + t) * QLD);
    const float4* wr4 = (const float4*)wrow[threadIdx.x >> 7];
    float acc = 0.f, den = 0.f;
    #pragma unroll
    for (int i = 0; i < 13; ++i) {
        float4 w = wr4[i];
        float4 qv = qrow[i];
        den += w.x + w.y + w.z + w.w;
        acc += qv.x * w.x + qv.y * w.y + qv.z * w.z + qv.w * w.w;
    }
    int w = (s * 32 + ((d >> 2) ^ (s & 31))) * 4 + (d & 3);
    qsp[(size_t)bt * 8192 + w] = acc / (den + 1e-20f);
}

// ---------------------------------------------------------------------------
// Shared helpers. XOR-4-swizzled LDS matrix layout: element (r,k) lives at
// M[r*64 + (((k>>2)^(r&15))<<2)+(k&3)].

__device__ __forceinline__ void dump_mat(float* M, const float4* v) {
    #pragma unroll
    for (int it = 0; it < 4; ++it) {
        int idx = it * 256 + (int)threadIdx.x;
        int r = idx >> 4, c4 = (idx & 15) << 2;
        *(float4*)&M[r * 64 + (c4 ^ ((r & 15) << 2))] = v[it];
    }
}

// stage one 64x64 row-major global matrix into swizzled LDS (coalesced)
__device__ __forceinline__ void stage1(float* M, const float* __restrict__ G) {
    const float4* g = (const float4*)G;
    float4 v[4];
    #pragma unroll
    for (int it = 0; it < 4; ++it) v[it] = g[it * 256 + (int)threadIdx.x];
    dump_mat(M, v);
}

// full-block mm (k=64, 4x4 tiles), swizzled LDS operands. acc[n][m] = sum_k Ra[n][k]*Rb[m][k]
// 4-wave (all 256 threads) — PROVEN: 2-wave bigger-tile variant regressed
// +6.6us (R9): fewer DS instrs but half the TLP loses to DS latency.
__device__ __forceinline__ void mm256_sw(float* acc, const float* Ra, const float* Rb) {
    int tid = threadIdx.x;
    int nl = tid >> 4, ml = tid & 15;
    int sxa = nl << 2, sxb = ml << 2;
    #pragma unroll
    for (int i = 0; i < 16; ++i) acc[i] = 0.f;
    #pragma unroll 4
    for (int k0 = 0; k0 < 64; k0 += 4) {
        float4 av[4], bv[4];
        #pragma unroll
        for (int i = 0; i < 4; ++i)
            av[i] = *(const float4*)&Ra[(nl + 16 * i) * 64 + (k0 ^ sxa)];
        #pragma unroll
        for (int j = 0; j < 4; ++j)
            bv[j] = *(const float4*)&Rb[(ml + 16 * j) * 64 + (k0 ^ sxb)];
        #pragma unroll
        for (int i = 0; i < 4; ++i)
            #pragma unroll
            for (int j = 0; j < 4; ++j)
                acc[i * 4 + j] += av[i].x * bv[j].x + av[i].y * bv[j].y
                                + av[i].z * bv[j].z + av[i].w * bv[j].w;
    }
}

// write full-block acc rows (acc[n][k] layout) into swizzled LDS
__device__ __forceinline__ void wr256_sw(float* M, const float* acc) {
    int nl = threadIdx.x >> 4, ml = threadIdx.x & 15;
    #pragma unroll
    for (int i = 0; i < 4; ++i)
        #pragma unroll
        for (int j = 0; j < 4; ++j) {
            int r = nl + 16 * i, k = ml + 16 * j;
            M[r * 64 + (((k & ~3) ^ ((r & 15) << 2)) | (k & 3))] = acc[i * 4 + j];
        }
}

// store 64x64 result row-major to global
__device__ __forceinline__ void store_mat(float* __restrict__ G, const float* acc) {
    int nl = threadIdx.x >> 4, ml = threadIdx.x & 15;
    #pragma unroll
    for (int i = 0; i < 4; ++i)
        #pragma unroll
        for (int j = 0; j < 4; ++j)
            G[(nl + 16 * i) * 64 + ml + 16 * j] = acc[i * 4 + j];
}

// store aa + fused loss from registers (proven epilogue)
__device__ __forceinline__ void store_loss(const float* acc, float* __restrict__ aa,
                                           float* __restrict__ out, float* red) {
    int tid = threadIdx.x;
    int nl = tid >> 4, ml = tid & 15;
    #pragma unroll
    for (int i = 0; i < 4; ++i)
        #pragma unroll
        for (int j = 0; j < 4; ++j)
            aa[(nl + 16 * i) * 64 + (ml + 16 * j)] = acc[i * 4 + j];
    int l = tid & 63;
    float part = 0.f;
    #pragma unroll
    for (int i = 0; i < 4; ++i) {
        float rsum = acc[i * 4 + 0] + acc[i * 4 + 1] + acc[i * 4 + 2] + acc[i * 4 + 3];
        rsum += __shfl_down(rsum, 8, 16);
        rsum += __shfl_down(rsum, 4, 16);
        rsum += __shfl_down(rsum, 2, 16);
        rsum += __shfl_down(rsum, 1, 16);
        float dv = __shfl(acc[5 * i], (l & 48) | nl, 64);
        if ((l & 15) == 0) part += logf(rsum + 6.4e-19f) - logf(dv + 1e-20f);
    }
    for (int off = 32; off; off >>= 1) part += __shfl_down(part, off);
    if (l == 0) red[tid >> 6] = part;
    __syncthreads();
    if (tid == 0) atomicAdd(out, (red[0] + red[1] + red[2] + red[3]) * (1.f / 128.f));
}

// Leader-fenced device barrier (proven R7). Participants <= 6 only
// (barrier cost ~linear in participants; 16 was +8.5us, 256 was +36us).
__device__ __forceinline__ void gbar(int* cnt, int target) {
    __syncthreads();
    if (threadIdx.x == 0) {
        __threadfence();
        __hip_atomic_fetch_add(cnt, 1, __ATOMIC_ACQ_REL, __HIP_MEMORY_SCOPE_AGENT);
        while (__hip_atomic_load(cnt, __ATOMIC_ACQUIRE, __HIP_MEMORY_SCOPE_AGENT) < target)
            __builtin_amdgcn_s_sleep(2);
        __threadfence();
    }
    __syncthreads();
}

// ---------------------------------------------------------------------------
// K3: fused As+zero_softmax+chain (R8 structure; B' staging hoisted — both
// staged operands are phase-A products available at bar0, so issuing both
// stage1 calls at phase entry takes the 2nd one's latency off the critical
// path between the two serial mms). grid = 6, block = 256, 2 device barriers.
__global__ void __launch_bounds__(256, 1)
k_tail(const float* __restrict__ qsp,
       float* __restrict__ a12T, float* __restrict__ a21, float* __restrict__ a21T,
       float* __restrict__ wsR1T, float* __restrict__ wsL,
       float* __restrict__ out, int* __restrict__ bar) {
    __shared__ float SM[16384];           // 64 KB, aliased per phase
    float* M0 = SM;
    float* M1 = SM + 4096;
    float* M2 = SM + 8192;
    float* M3 = SM + 12288;
    const int tid = threadIdx.x;
    const int blk = blockIdx.x;
    const int t = blk % 3, b = blk / 3;

    // ---------------- phase A: As + zero_softmax -------------------------
    {
        float4* qaT4 = (float4*)SM;              // [64][32] swizzled (s-major)
        float4* qbT4 = (float4*)SM + 2048;
        {
            const float4* gA = (const float4*)(qsp + (size_t)(b * 4 + t) * 8192);
            const float4* gB = (const float4*)(qsp + (size_t)(b * 4 + t + 1) * 8192);
            #pragma unroll
            for (int it = 0; it < 8; ++it) {
                int idx = it * 256 + tid;
                qaT4[idx] = gA[idx];
                qbT4[idx] = gB[idx];
            }
        }
        __syncthreads();

        const int nl = tid >> 4, ml = tid & 15;
        float acc[16];
        #pragma unroll
        for (int i = 0; i < 16; ++i) acc[i] = 0.f;
        #pragma unroll 8
        for (int k4 = 0; k4 < 32; ++k4) {
            float4 av[4], bv[4];
            #pragma unroll
            for (int i = 0; i < 4; ++i) { int n = nl + 16 * i; av[i] = qaT4[n * 32 + (k4 ^ (n & 31))]; }
            #pragma unroll
            for (int j = 0; j < 4; ++j) { int m = ml + 16 * j; bv[j] = qbT4[m * 32 + (k4 ^ (m & 31))]; }
            #pragma unroll
            for (int i = 0; i < 4; ++i)
                #pragma unroll
                for (int j = 0; j < 4; ++j)
                    acc[i * 4 + j] += av[i].x * bv[j].x + av[i].y * bv[j].y
                                    + av[i].z * bv[j].z + av[i].w * bv[j].w;
        }
        __syncthreads();

        float* eb = (float*)qaT4;          // [64][65]
        float* rs = (float*)qbT4;          // [64]
        float* cs = rs + 64;               // [64]
        #pragma unroll
        for (int i = 0; i < 4; ++i)
            #pragma unroll
            for (int j = 0; j < 4; ++j) {
                int n = nl + 16 * i, m = ml + 16 * j;
                float x = acc[i * 4 + j] * (1.f / 0.07f);
                float e = expf(x) - 1.f;
                eb[n * 65 + m] = e * e;
            }
        __syncthreads();
        if (tid < 128) {
            int r = tid & 63; bool isrow = tid < 64;
            float a = 0.f;
            #pragma unroll
            for (int k = 0; k < 64; ++k) a += isrow ? eb[r * 65 + k] : eb[k * 65 + r];
            (isrow ? rs : cs)[r] = a + 1e-5f;
        }
        __syncthreads();
        // t==0: A12_0 -> LDS M3 (local), A21_0^T -> global.
        // t==1: A12_1^T -> global, A21_1 -> LDS M3 (local).
        // t==2: both -> global.
        float* p12T = a12T + (b * 3 + t) * 4096;
        float* p21  = a21  + (b * 3 + t) * 4096;
        float* p21T = a21T + (b * 3 + t) * 4096;
        #pragma unroll
        for (int i = 0; i < 4; ++i)
            #pragma unroll
            for (int j = 0; j < 4; ++j) {
                int n = nl + 16 * i, m = ml + 16 * j;
                float v   = eb[n * 65 + m];
                float v12 = v / rs[n];           // A12[n][m]
                float v21 = v / cs[m];           // A21[m][n]
                if (t == 0) {
                    M3[n * 64 + (((m & ~3) ^ ((n & 15) << 2)) | (m & 3))] = v12;
                    p21T[n * 64 + m] = v21;
                } else if (t == 1) {
                    p12T[m * 64 + n] = v12;
                    M3[m * 64 + (((n & ~3) ^ ((m & 15) << 2)) | (n & 3))] = v21;
                } else {
                    p12T[m * 64 + n] = v12;
                    p21 [m * 64 + n] = v21;
                }
            }
    }
    gbar(bar + 0, 6);
    if (t == 2) return;                   // blocks 2,5 done (arrived at bar0)
    const bool odd = (t == 1);

    // ---------------- phase B': 2 mms per block; BOTH operands staged at
    // phase entry (hoisted — available since bar0) -------------------------
    if (!odd) {
        // P = A12_0(M3 local) @ A12_1 ; L = P @ A12_2 -> wsL
        stage1(M0, a12T + (b * 3 + 1) * 4096);    // A12_1^T rows
        stage1(M2, a12T + (b * 3 + 2) * 4096);    // A12_2^T rows (hoisted)
        __syncthreads();
        float accP[16];
        mm256_sw(accP, M3, M0);                   // P
        wr256_sw(M1, accP);                       // P rows, local
        __syncthreads();
        float accL[16];
        mm256_sw(accL, M1, M2);                   // L = P @ A12_2
        store_mat(wsL + b * 4096, accL);          // partner needs L
    } else {
        // R1T = A21_0^T @ A21_1(M3 local) ; RT = R1T @ A21_2^T (local)
        stage1(M0, a21T + (b * 3 + 0) * 4096);    // A21_0^T rows
        stage1(M2, a21 + (b * 3 + 2) * 4096);     // A21_2 rows (hoisted)
        __syncthreads();
        float accR[16];
        mm256_sw(accR, M0, M3);                   // R1T
        store_mat(wsR1T + b * 4096, accR);        // partner needs R1T
        wr256_sw(M1, accR);                       // R1T rows, local
        __syncthreads();
        float accRT[16];
        mm256_sw(accRT, M1, M2);                  // RT[n][m] = (A21_2@R1)^T
        wr256_sw(M0, accRT);                      // RT rows, local (Rb of aa2)
    }
    gbar(bar + 1, 4);

    // ---------------- phase C': final mms + fused loss ---------------------
    if (!odd) {
        // aa1_b = P @ R1 : Ra = M1 (P, resident), Rb = R1T_b staged
        stage1(M2, wsR1T + b * 4096);
        __syncthreads();
        float acc[16];
        mm256_sw(acc, M1, M2);
        store_loss(acc, out + 1 + b * 4096, out, M0);
    } else {
        // aa2_b = L @ R : Ra = L_b staged, Rb = M0 (RT, resident)
        stage1(M2, wsL + b * 4096);
        __syncthreads();
        float acc[16];
        mm256_sw(acc, M2, M0);
        store_loss(acc, out + 1 + (2 + b) * 4096, out, M1);
    }
}

// ---------------------------------------------------------------------------
extern "C" void kernel_launch(void* const* d_in, const int* in_sizes, int n_in,
                              void* d_out, int out_size, void* d_ws, size_t ws_size,
                              hipStream_t stream) {
    const float* feats = (const float*)d_in[0];
    const float* Wh    = (const float*)d_in[1];
    const int*   mask  = (const int*)d_in[2];
    float* out = (float*)d_out;
    float* ws  = (float*)d_ws;

    float* q       = ws + OFF_Q;
    float* qsp     = ws + OFF_QSP;
    float* a12T    = ws + OFF_A12T;
    float* a21     = ws + OFF_A21;
    float* a21T    = ws + OFF_A21T;
    float* wsR1T   = ws + OFF_R1T;
    float* wsL     = ws + OFF_L;
    float* h       = ws + OFF_H;
    int*   bar     = (int*)(ws + OFF_BAR);

    k_front<<<98 + 512, 256, 0, stream>>>(mask, feats, Wh, h, q);
    k_qsp<<<256, 256, 0, stream>>>(q, h, qsp, out, bar);
    k_tail<<<6, 256, 0, stream>>>(qsp, a12T, a21, a21T,
                                  wsR1T, wsL, out, bar);
}